// Round 7
// baseline (763.492 us; speedup 1.0000x reference)
//
#include <hip/hip_runtime.h>
#include <cmath>

// ---------------- problem constants ----------------
constexpr int B_  = 2;
constexpr int C_  = 256;   // NDIM
constexpr int T_  = 512;
constexpr int F_  = 64;
constexpr int N_  = B_ * F_;     // 128 sequences
constexpr int H_  = 8;
constexpr int DH  = 32;          // head dim
constexpr int FF  = 1024;        // R*NDIM
constexpr int WLEN = 128;
constexpr int M_  = N_ * T_;     // 65536 rows
constexpr long long NTC = (long long)N_ * T_ * C_;  // 16777216 elements

typedef _Float16 half8 __attribute__((ext_vector_type(8)));
typedef _Float16 half4v __attribute__((ext_vector_type(4)));
typedef float f32x4 __attribute__((ext_vector_type(4)));

// ---------------- fp32 -> fp16 convert (weights) ----------------
__global__ __launch_bounds__(256) void k_cvt16(const float* __restrict__ in,
                                               _Float16* __restrict__ out, int n4) {
    int i = blockIdx.x * 256 + threadIdx.x;
    if (i < n4) {
        float4 v = ((const float4*)in)[i];
        half4v h = { (_Float16)v.x, (_Float16)v.y, (_Float16)v.z, (_Float16)v.w };
        *(half4v*)&out[(size_t)i * 4] = h;
    }
}

// ---------------- transpose in: x (B,C,T,F) -> xs (N=B*F, T, C) ----------------
__global__ __launch_bounds__(256) void k_transpose_in(const float* __restrict__ x,
                                                      float* __restrict__ xs) {
    __shared__ float tile[32][33];
    const int bz = blockIdx.z;            // b*T + t
    const int b = bz >> 9, t = bz & 511;
    const int c0 = blockIdx.x * 32, f0 = blockIdx.y * 32;
    const int tx = threadIdx.x, ty = threadIdx.y;   // 32 x 8
#pragma unroll
    for (int i = 0; i < 4; ++i) {
        int c = c0 + ty + i * 8;
        tile[ty + i * 8][tx] = x[(((size_t)(b * C_ + c)) * T_ + t) * F_ + f0 + tx];
    }
    __syncthreads();
#pragma unroll
    for (int i = 0; i < 4; ++i) {
        int f = f0 + ty + i * 8;
        xs[(((size_t)(b * F_ + f)) * T_ + t) * C_ + c0 + tx] = tile[tx][ty + i * 8];
    }
}

// ---------------- transpose out: tmp (N,T,C) -> out (B,C,T,F) ----------------
__global__ __launch_bounds__(256) void k_transpose_out(const float* __restrict__ tmp,
                                                       float* __restrict__ out) {
    __shared__ float tile[32][33];
    const int bz = blockIdx.z;
    const int b = bz >> 9, t = bz & 511;
    const int c0 = blockIdx.x * 32, f0 = blockIdx.y * 32;
    const int tx = threadIdx.x, ty = threadIdx.y;
#pragma unroll
    for (int i = 0; i < 4; ++i) {
        int f = f0 + ty + i * 8;
        tile[ty + i * 8][tx] = tmp[(((size_t)(b * F_ + f)) * T_ + t) * C_ + c0 + tx];
    }
    __syncthreads();
#pragma unroll
    for (int i = 0; i < 4; ++i) {
        int c = c0 + ty + i * 8;
        out[(((size_t)(b * C_ + c)) * T_ + t) * F_ + f0 + tx] = tile[tx][ty + i * 8];
    }
}

// ---------------- MFMA GEMM: out[m][n] = sum_k A[m][k]*W[n][k] + bias[n] ----------------
enum { EPI_NONE = 0, EPI_RES = 1, EPI_GELU = 2 };

__device__ __forceinline__ float gelu_f(float v) {
    return 0.5f * v * (1.0f + erff(v * 0.70710678118654752f));
}

// BM=BN=128, BK=32, 256 threads = 4 waves, each wave 64x64 via 4x4 16x16x32 MFMA frags.
// XCD-chunked swizzle: each XCD owns gridDim.y/8 m-tiles and sweeps n-tiles fast
// (A-panel stays in its local L2). Requires gridDim.y % 8 == 0.
// Epilogue is LDS-staged for full-line coalesced global stores.
template <int EPI, bool A_F16, bool OUT_F16>
__global__ __launch_bounds__(256) void k_gemm_mfma(const void* __restrict__ Aptr,
                                                   const _Float16* __restrict__ W,
                                                   const float* __restrict__ bias,
                                                   const float* __restrict__ resid,
                                                   void* __restrict__ outp,
                                                   int Nout, int K) {
    __shared__ __align__(16) unsigned char smem[20480];
    _Float16 (*As)[40] = (_Float16(*)[40])smem;            // 128x40 halves = 10240 B
    _Float16 (*Bs)[40] = (_Float16(*)[40])(smem + 10240);  // 128x40 halves

    // ---- XCD-chunked block swizzle ----
    const int nx = gridDim.x;
    const int flat = blockIdx.x + nx * blockIdx.y;   // HW dispatch order (x fastest)
    const int xcd = flat & 7;
    const int s = flat >> 3;
    const int mpx = gridDim.y >> 3;                  // m-tiles per XCD
    const int n0 = (s % nx) * 128;
    const int m0 = (xcd * mpx + s / nx) * 128;

    const int tid  = threadIdx.x;
    const int lane = tid & 63;
    const int wid  = tid >> 6;
    const int wm = wid >> 1, wn = wid & 1;
    const int g = lane >> 4, c = lane & 15;
    const int srow = tid >> 1;           // 0..127
    const int skh  = (tid & 1) * 16;     // 0 or 16

    f32x4 acc[4][4] = {};

    for (int k0 = 0; k0 < K; k0 += 32) {
        if (A_F16) {
            const _Float16* ap = (const _Float16*)Aptr + (size_t)(m0 + srow) * K + k0 + skh;
            half8 a0 = ((const half8*)ap)[0];
            half8 a1 = ((const half8*)ap)[1];
            *(half8*)&As[srow][skh]     = a0;
            *(half8*)&As[srow][skh + 8] = a1;
        } else {
            const float* ap = (const float*)Aptr + (size_t)(m0 + srow) * K + k0 + skh;
            float4 v0 = ((const float4*)ap)[0];
            float4 v1 = ((const float4*)ap)[1];
            float4 v2 = ((const float4*)ap)[2];
            float4 v3 = ((const float4*)ap)[3];
            half8 a0 = { (_Float16)v0.x, (_Float16)v0.y, (_Float16)v0.z, (_Float16)v0.w,
                         (_Float16)v1.x, (_Float16)v1.y, (_Float16)v1.z, (_Float16)v1.w };
            half8 a1 = { (_Float16)v2.x, (_Float16)v2.y, (_Float16)v2.z, (_Float16)v2.w,
                         (_Float16)v3.x, (_Float16)v3.y, (_Float16)v3.z, (_Float16)v3.w };
            *(half8*)&As[srow][skh]     = a0;
            *(half8*)&As[srow][skh + 8] = a1;
        }
        {
            const _Float16* bp = W + (size_t)(n0 + srow) * K + k0 + skh;
            half8 b0 = ((const half8*)bp)[0];
            half8 b1 = ((const half8*)bp)[1];
            *(half8*)&Bs[srow][skh]     = b0;
            *(half8*)&Bs[srow][skh + 8] = b1;
        }
        __syncthreads();

        half8 af[4], bf[4];
#pragma unroll
        for (int mi = 0; mi < 4; ++mi)
            af[mi] = *(const half8*)&As[wm * 64 + mi * 16 + c][g * 8];
#pragma unroll
        for (int ni = 0; ni < 4; ++ni)
            bf[ni] = *(const half8*)&Bs[wn * 64 + ni * 16 + c][g * 8];
#pragma unroll
        for (int mi = 0; mi < 4; ++mi)
#pragma unroll
            for (int ni = 0; ni < 4; ++ni)
                acc[mi][ni] = __builtin_amdgcn_mfma_f32_16x16x32_f16(
                    af[mi], bf[ni], acc[mi][ni], 0, 0, 0);
        __syncthreads();
    }

    // ---- LDS-staged coalesced epilogue ----
    // acc[mi][ni][r] = C[m0 + wm*64 + mi*16 + 4g + r][n0 + wn*64 + ni*16 + c]
    if (OUT_F16) {
        _Float16 (*C16)[68] = (_Float16(*)[68])smem;   // 128x68 halves = 17408 B
#pragma unroll
        for (int p = 0; p < 2; ++p) {
            __syncthreads();
            if (wn == p) {
#pragma unroll
                for (int ni = 0; ni < 4; ++ni) {
                    const float bv = bias[n0 + p * 64 + ni * 16 + c];
#pragma unroll
                    for (int mi = 0; mi < 4; ++mi)
#pragma unroll
                        for (int r = 0; r < 4; ++r) {
                            float v = acc[mi][ni][r] + bv;
                            if (EPI == EPI_GELU) v = gelu_f(v);
                            C16[wm * 64 + mi * 16 + 4 * g + r][ni * 16 + c] = (_Float16)v;
                        }
                }
            }
            __syncthreads();
            const int row = tid >> 1, coff = (tid & 1) * 32;
            _Float16* dst = (_Float16*)outp + (size_t)(m0 + row) * Nout + n0 + p * 64 + coff;
#pragma unroll
            for (int jj = 0; jj < 4; ++jj)
                *(half8*)&dst[jj * 8] = *(const half8*)&C16[row][coff + jj * 8];
        }
    } else {
        float (*C32)[33] = (float(*)[33])smem;         // 128x33 floats = 16896 B
#pragma unroll
        for (int p2 = 0; p2 < 4; ++p2) {
            __syncthreads();
            if (wn == (p2 >> 1)) {
#pragma unroll
                for (int q = 0; q < 2; ++q) {
                    const int ni = (p2 & 1) * 2 + q;
                    const float bv = bias[n0 + wn * 64 + ni * 16 + c];
#pragma unroll
                    for (int mi = 0; mi < 4; ++mi)
#pragma unroll
                        for (int r = 0; r < 4; ++r)
                            C32[wm * 64 + mi * 16 + 4 * g + r][q * 16 + c] =
                                acc[mi][ni][r] + bv;
                }
            }
            __syncthreads();
            const int row = tid >> 1, c0 = (tid & 1) * 16;
            const int gcol = n0 + (p2 >> 1) * 64 + (p2 & 1) * 32 + c0;
            float* dst = (float*)outp + (size_t)(m0 + row) * Nout + gcol;
            const float* rsd = (EPI == EPI_RES)
                                   ? &resid[(size_t)(m0 + row) * Nout + gcol]
                                   : nullptr;
#pragma unroll
            for (int jj = 0; jj < 4; ++jj) {
                float4 v = *(const float4*)&C32[row][c0 + jj * 4];
                if (EPI == EPI_RES) {
                    float4 rv = *(const float4*)&rsd[jj * 4];
                    v.x += rv.x; v.y += rv.y; v.z += rv.z; v.w += rv.w;
                }
                *(float4*)&dst[jj * 4] = v;
            }
        }
    }
}

// ---------------- MFMA windowed causal attention ----------------
__global__ __launch_bounds__(256) void k_attn_mfma(const _Float16* __restrict__ qkv,
                                                   _Float16* __restrict__ ctx) {
    __shared__ _Float16 Vt[32][200];   // V^T: [dim][key]
    __shared__ _Float16 Pl[64][200];   // P:   [query][key]
    const int qt = blockIdx.x;
    const int nh = blockIdx.y;
    const int n = nh >> 3, h = nh & 7;     // group-local sequence
    const int q0 = qt * 64;
    const int jlo = (q0 >= WLEN - 1) ? (q0 - (WLEN - 1)) : 0;
    const int tid = threadIdx.x;
    const int w = tid >> 6;
    const int lane = tid & 63;
    const int g = lane >> 4, c = lane & 15;
    const size_t base = (size_t)n * T_ * (3 * C_);
    const int hq = h * DH;

    for (int idx = tid; idx < 192 * 4; idx += 256) {
        int rj = idx >> 2, dp = (idx & 3) * 8;
        int vr = jlo + rj; if (vr > T_ - 1) vr = T_ - 1;
        half8 vv = *(const half8*)&qkv[base + (size_t)vr * (3 * C_) + 2 * C_ + hq + dp];
#pragma unroll
        for (int u = 0; u < 8; ++u) Vt[dp + u][rj] = vv[u];
    }

    half8 qf = *(const half8*)&qkv[base + (size_t)(q0 + w * 16 + c) * (3 * C_) + hq + g * 8];

    f32x4 s[12];
#pragma unroll
    for (int t = 0; t < 12; ++t) {
        int jr = jlo + 16 * t + c; if (jr > T_ - 1) jr = T_ - 1;
        half8 kf = *(const half8*)&qkv[base + (size_t)jr * (3 * C_) + C_ + hq + g * 8];
        f32x4 z = {0.f, 0.f, 0.f, 0.f};
        s[t] = __builtin_amdgcn_mfma_f32_16x16x32_f16(qf, kf, z, 0, 0, 0);
    }

    const float scale = 0.17677669529663687f;   // 1/sqrt(32)
    float invl[4];
#pragma unroll
    for (int r = 0; r < 4; ++r) {
        const int i = q0 + w * 16 + 4 * g + r;
        float m = -3.0e38f;
        float sv[12];
#pragma unroll
        for (int t = 0; t < 12; ++t) {
            int j = jlo + 16 * t + c;
            bool ok = (j <= i) && (j > i - WLEN);
            float v = ok ? s[t][r] * scale : -3.0e38f;
            sv[t] = v;
            m = fmaxf(m, v);
        }
        m = fmaxf(m, __shfl_xor(m, 1));
        m = fmaxf(m, __shfl_xor(m, 2));
        m = fmaxf(m, __shfl_xor(m, 4));
        m = fmaxf(m, __shfl_xor(m, 8));
        float l = 0.f;
#pragma unroll
        for (int t = 0; t < 12; ++t) {
            float p = (sv[t] > -1.0e38f) ? __expf(sv[t] - m) : 0.f;
            l += p;
            Pl[w * 16 + 4 * g + r][16 * t + c] = (_Float16)p;
        }
        l += __shfl_xor(l, 1);
        l += __shfl_xor(l, 2);
        l += __shfl_xor(l, 4);
        l += __shfl_xor(l, 8);
        invl[r] = 1.0f / l;
    }
    __syncthreads();

    f32x4 o0 = {0.f, 0.f, 0.f, 0.f}, o1 = {0.f, 0.f, 0.f, 0.f};
#pragma unroll
    for (int ks = 0; ks < 6; ++ks) {
        half8 pa = *(const half8*)&Pl[w * 16 + c][32 * ks + 8 * g];
        half8 b0 = *(const half8*)&Vt[c][32 * ks + 8 * g];
        half8 b1 = *(const half8*)&Vt[c + 16][32 * ks + 8 * g];
        o0 = __builtin_amdgcn_mfma_f32_16x16x32_f16(pa, b0, o0, 0, 0, 0);
        o1 = __builtin_amdgcn_mfma_f32_16x16x32_f16(pa, b1, o1, 0, 0, 0);
    }
#pragma unroll
    for (int r = 0; r < 4; ++r) {
        const int i = q0 + w * 16 + 4 * g + r;
        _Float16* op = &ctx[((size_t)n * T_ + i) * C_ + hq];
        op[c]      = (_Float16)(o0[r] * invl[r]);
        op[c + 16] = (_Float16)(o1[r] * invl[r]);
    }
}

// ---------------- LayerNorm over last dim C=256; one wave per row ----------------
__global__ __launch_bounds__(256) void k_ln(const float* __restrict__ in,
                                            const float* __restrict__ g,
                                            const float* __restrict__ b,
                                            float* __restrict__ out) {
    const int row = blockIdx.x * 4 + (threadIdx.x >> 6);
    const int lane = threadIdx.x & 63;
    const float4 v = *(const float4*)&in[(size_t)row * C_ + lane * 4];
    float s = v.x + v.y + v.z + v.w;
    float sq = v.x * v.x + v.y * v.y + v.z * v.z + v.w * v.w;
#pragma unroll
    for (int off = 1; off < 64; off <<= 1) {
        s += __shfl_xor(s, off);
        sq += __shfl_xor(sq, off);
    }
    float mu = s * (1.0f / C_);
    float var = sq * (1.0f / C_) - mu * mu;
    if (var < 0.f) var = 0.f;
    float rstd = rsqrtf(var + 1e-5f);
    float4 gv = *(const float4*)&g[lane * 4];
    float4 bv = *(const float4*)&b[lane * 4];
    float4 o;
    o.x = (v.x - mu) * rstd * gv.x + bv.x;
    o.y = (v.y - mu) * rstd * gv.y + bv.y;
    o.z = (v.z - mu) * rstd * gv.z + bv.z;
    o.w = (v.w - mu) * rstd * gv.w + bv.w;
    *(float4*)&out[(size_t)row * C_ + lane * 4] = o;
}

// ---------------- launch ----------------
extern "C" void kernel_launch(void* const* d_in, const int* in_sizes, int n_in,
                              void* d_out, int out_size, void* d_ws, size_t ws_size,
                              hipStream_t stream) {
    (void)in_sizes; (void)n_in; (void)out_size;
    const float* x     = (const float*)d_in[0];
    const float* in_w  = (const float*)d_in[1];
    const float* in_b  = (const float*)d_in[2];
    const float* out_w = (const float*)d_in[3];
    const float* out_b = (const float*)d_in[4];
    const float* ln1g  = (const float*)d_in[5];
    const float* ln1b  = (const float*)d_in[6];
    const float* w1    = (const float*)d_in[7];
    const float* b1    = (const float*)d_in[8];
    const float* w2    = (const float*)d_in[9];
    const float* b2    = (const float*)d_in[10];
    const float* ln2g  = (const float*)d_in[11];
    const float* ln2b  = (const float*)d_in[12];
    float* out = (float*)d_out;
    float* ws  = (float*)d_ws;

    // Workspace (floats):
    //   A  = [0, NTC)       : xs, then nrm (after LN1)
    //   B  = [NTC, 2NTC)    : qkv16 (fp16) -> res1 -> tmp2
    //   C  = [2NTC, ...)    : h16 (fp16), then W16 tail
    // ctx16 / res2 live in d_out.
    const int G = (ws_size >= (size_t)3 * NTC * sizeof(float)) ? 4 : 8;
    const int Ng = N_ / G;
    const long long Mg = (long long)Ng * T_;

    float* xs   = ws;
    float* nrm  = ws;
    _Float16* qkv16 = (_Float16*)(ws + NTC);
    float* res1 = ws + NTC;
    float* tmp2 = ws + NTC;
    _Float16* h16 = (_Float16*)(ws + 2 * NTC);
    float* wtail = ws + 2 * NTC + (size_t)Mg * 512;
    _Float16* w16_in  = (_Float16*)wtail;           // 196608
    _Float16* w16_out = w16_in + 196608;            // 65536
    _Float16* w16_1   = w16_out + 65536;            // 262144
    _Float16* w16_2   = w16_1 + 262144;             // 262144
    _Float16* ctx16 = (_Float16*)d_out;             // d_out as scratch (fp16)
    float* res2 = out;                              // d_out as scratch (fp32)

    // weight conversion
    k_cvt16<<<192, 256, 0, stream>>>(in_w,  w16_in,  196608 / 4);
    k_cvt16<<<64,  256, 0, stream>>>(out_w, w16_out, 65536 / 4);
    k_cvt16<<<256, 256, 0, stream>>>(w1,    w16_1,   262144 / 4);
    k_cvt16<<<256, 256, 0, stream>>>(w2,    w16_2,   262144 / 4);

    dim3 tb(32, 8);
    k_transpose_in<<<dim3(C_ / 32, F_ / 32, B_ * T_), tb, 0, stream>>>(x, xs);

    // QKV projection + attention, per sequence-group
    for (int g = 0; g < G; ++g) {
        const float* xs_g = xs + (size_t)g * Mg * C_;
        k_gemm_mfma<EPI_NONE, false, true><<<dim3(768 / 128, Mg / 128), 256, 0, stream>>>(
            xs_g, w16_in, in_b, nullptr, qkv16, 3 * C_, C_);
        k_attn_mfma<<<dim3(T_ / 64, Ng * H_), 256, 0, stream>>>(
            qkv16, ctx16 + (size_t)g * Mg * C_);
    }

    // out projection + residual(xs), full M (A = fp16 ctx)
    k_gemm_mfma<EPI_RES, true, false><<<dim3(C_ / 128, M_ / 128), 256, 0, stream>>>(
        ctx16, w16_out, out_b, xs, res1, C_, C_);

    // LN1: res1 -> nrm
    k_ln<<<M_ / 4, 256, 0, stream>>>(res1, ln1g, ln1b, nrm);

    // FFN per row-group
    for (int g = 0; g < G; ++g) {
        const float* nrm_g = nrm + (size_t)g * Mg * C_;
        k_gemm_mfma<EPI_GELU, false, true><<<dim3(FF / 128, Mg / 128), 256, 0, stream>>>(
            nrm_g, w16_1, b1, nullptr, h16, FF, C_);
        k_gemm_mfma<EPI_RES, true, false><<<dim3(C_ / 128, Mg / 128), 256, 0, stream>>>(
            h16, w16_2, b2, nrm_g, res2 + (size_t)g * Mg * C_, C_, FF);
    }

    // LN2: res2(d_out) -> tmp2
    k_ln<<<M_ / 4, 256, 0, stream>>>(res2, ln2g, ln2b, tmp2);

    // back to (B,C,T,F)
    k_transpose_out<<<dim3(C_ / 32, F_ / 32, B_ * T_), tb, 0, stream>>>(tmp2, out);
}

// Round 8
// 716.348 us; speedup vs baseline: 1.0658x; 1.0658x over previous
//
#include <hip/hip_runtime.h>
#include <cmath>

// ---------------- problem constants ----------------
constexpr int B_  = 2;
constexpr int C_  = 256;   // NDIM
constexpr int T_  = 512;
constexpr int F_  = 64;
constexpr int N_  = B_ * F_;     // 128 sequences
constexpr int H_  = 8;
constexpr int DH  = 32;          // head dim
constexpr int FF  = 1024;        // R*NDIM
constexpr int WLEN = 128;
constexpr int M_  = N_ * T_;     // 65536 rows
constexpr long long NTC = (long long)N_ * T_ * C_;  // 16777216 elements

typedef _Float16 half8 __attribute__((ext_vector_type(8)));
typedef _Float16 half4v __attribute__((ext_vector_type(4)));
typedef float f32x4 __attribute__((ext_vector_type(4)));

// ---------------- fp32 -> fp16 convert (weights) ----------------
__global__ __launch_bounds__(256) void k_cvt16(const float* __restrict__ in,
                                               _Float16* __restrict__ out, int n4) {
    int i = blockIdx.x * 256 + threadIdx.x;
    if (i < n4) {
        float4 v = ((const float4*)in)[i];
        half4v h = { (_Float16)v.x, (_Float16)v.y, (_Float16)v.z, (_Float16)v.w };
        *(half4v*)&out[(size_t)i * 4] = h;
    }
}

// ---------------- transpose in: x (B,C,T,F) -> xs (N=B*F, T, C) ----------------
__global__ __launch_bounds__(256) void k_transpose_in(const float* __restrict__ x,
                                                      float* __restrict__ xs) {
    __shared__ float tile[32][33];
    const int bz = blockIdx.z;            // b*T + t
    const int b = bz >> 9, t = bz & 511;
    const int c0 = blockIdx.x * 32, f0 = blockIdx.y * 32;
    const int tx = threadIdx.x, ty = threadIdx.y;   // 32 x 8
#pragma unroll
    for (int i = 0; i < 4; ++i) {
        int c = c0 + ty + i * 8;
        tile[ty + i * 8][tx] = x[(((size_t)(b * C_ + c)) * T_ + t) * F_ + f0 + tx];
    }
    __syncthreads();
#pragma unroll
    for (int i = 0; i < 4; ++i) {
        int f = f0 + ty + i * 8;
        xs[(((size_t)(b * F_ + f)) * T_ + t) * C_ + c0 + tx] = tile[tx][ty + i * 8];
    }
}

// ---------------- transpose out: tmp (N,T,C) -> out (B,C,T,F) ----------------
__global__ __launch_bounds__(256) void k_transpose_out(const float* __restrict__ tmp,
                                                       float* __restrict__ out) {
    __shared__ float tile[32][33];
    const int bz = blockIdx.z;
    const int b = bz >> 9, t = bz & 511;
    const int c0 = blockIdx.x * 32, f0 = blockIdx.y * 32;
    const int tx = threadIdx.x, ty = threadIdx.y;
#pragma unroll
    for (int i = 0; i < 4; ++i) {
        int f = f0 + ty + i * 8;
        tile[ty + i * 8][tx] = tmp[(((size_t)(b * F_ + f)) * T_ + t) * C_ + c0 + tx];
    }
    __syncthreads();
#pragma unroll
    for (int i = 0; i < 4; ++i) {
        int c = c0 + ty + i * 8;
        out[(((size_t)(b * C_ + c)) * T_ + t) * F_ + f0 + tx] = tile[tx][ty + i * 8];
    }
}

// ---------------- MFMA GEMM: out[m][n] = sum_k A[m][k]*W[n][k] + bias[n] ----------------
enum { EPI_NONE = 0, EPI_RES = 1, EPI_GELU = 2 };

__device__ __forceinline__ float gelu_f(float v) {
    return 0.5f * v * (1.0f + erff(v * 0.70710678118654752f));
}

// BM=BN=128, BK=32, 256 threads = 4 waves, each wave 64x64 via 4x4 16x16x32 MFMA frags.
// 2-phase pipelined K-loop: double-buffered LDS; tile t+1's global loads issue
// before tile t's MFMAs (vmcnt lands at the ds_write after the MFMAs), one
// barrier per iteration. XCD-chunked block swizzle for L2 A-panel reuse.
// LDS-staged coalesced epilogue (requires K/32 even: last tile is in buffer 1,
// epilogue reuses buffer 0).
template <int EPI, bool A_F16, bool OUT_F16>
__global__ __launch_bounds__(256) void k_gemm_mfma(const void* __restrict__ Aptr,
                                                   const _Float16* __restrict__ W,
                                                   const float* __restrict__ bias,
                                                   const float* __restrict__ resid,
                                                   void* __restrict__ outp,
                                                   int Nout, int K) {
    __shared__ __align__(16) unsigned char smem[40960];  // 2 x (As 10240 + Bs 10240)

    // ---- XCD-chunked block swizzle ----
    const int nx = gridDim.x;
    const int flat = blockIdx.x + nx * blockIdx.y;   // HW dispatch order (x fastest)
    const int xcd = flat & 7;
    const int s = flat >> 3;
    const int mpx = gridDim.y >> 3;                  // m-tiles per XCD
    const int n0 = (s % nx) * 128;
    const int m0 = (xcd * mpx + s / nx) * 128;

    const int tid  = threadIdx.x;
    const int lane = tid & 63;
    const int wid  = tid >> 6;
    const int wm = wid >> 1, wn = wid & 1;
    const int g = lane >> 4, c = lane & 15;
    const int srow = tid >> 1;           // 0..127
    const int skh  = (tid & 1) * 16;     // 0 or 16

    const char* abase = (const char*)Aptr +
        (A_F16 ? ((size_t)(m0 + srow) * K + skh) * 2
               : ((size_t)(m0 + srow) * K + skh) * 4);
    const _Float16* bbase = W + (size_t)(n0 + srow) * K + skh;

    f32x4 acc[4][4] = {};

    // ---- prologue: stage tile 0 into buffer 0 ----
    {
        _Float16 (*As)[40] = (_Float16(*)[40])(smem);
        _Float16 (*Bs)[40] = (_Float16(*)[40])(smem + 10240);
        if (A_F16) {
            const half8* ap = (const half8*)abase;
            *(half8*)&As[srow][skh]     = ap[0];
            *(half8*)&As[srow][skh + 8] = ap[1];
        } else {
            const float4* ap = (const float4*)abase;
            float4 v0 = ap[0], v1 = ap[1], v2 = ap[2], v3 = ap[3];
            half8 a0 = { (_Float16)v0.x, (_Float16)v0.y, (_Float16)v0.z, (_Float16)v0.w,
                         (_Float16)v1.x, (_Float16)v1.y, (_Float16)v1.z, (_Float16)v1.w };
            half8 a1 = { (_Float16)v2.x, (_Float16)v2.y, (_Float16)v2.z, (_Float16)v2.w,
                         (_Float16)v3.x, (_Float16)v3.y, (_Float16)v3.z, (_Float16)v3.w };
            *(half8*)&As[srow][skh]     = a0;
            *(half8*)&As[srow][skh + 8] = a1;
        }
        const half8* bp = (const half8*)bbase;
        *(half8*)&Bs[srow][skh]     = bp[0];
        *(half8*)&Bs[srow][skh + 8] = bp[1];
    }
    __syncthreads();

    const int nt = K >> 5;
    float4 pv0, pv1, pv2, pv3;
    half8 av0, av1, bv0, bv1;

    for (int t = 0; t < nt; ++t) {
        const unsigned cur = (unsigned)t & 1u;
        _Float16 (*As)[40] = (_Float16(*)[40])(smem + cur * 20480);
        _Float16 (*Bs)[40] = (_Float16(*)[40])(smem + cur * 20480 + 10240);
        const bool pf = (t + 1 < nt);

        // ---- issue next tile's global loads (stay in flight across MFMAs) ----
        if (pf) {
            const int k0 = (t + 1) << 5;
            if (A_F16) {
                const half8* ap = (const half8*)(abase + (size_t)k0 * 2);
                av0 = ap[0]; av1 = ap[1];
            } else {
                const float4* ap = (const float4*)(abase + (size_t)k0 * 4);
                pv0 = ap[0]; pv1 = ap[1]; pv2 = ap[2]; pv3 = ap[3];
            }
            const half8* bp = (const half8*)(bbase + k0);
            bv0 = bp[0]; bv1 = bp[1];
        }

        // ---- compute current tile ----
        half8 af[4], bf[4];
#pragma unroll
        for (int mi = 0; mi < 4; ++mi)
            af[mi] = *(const half8*)&As[wm * 64 + mi * 16 + c][g * 8];
#pragma unroll
        for (int ni = 0; ni < 4; ++ni)
            bf[ni] = *(const half8*)&Bs[wn * 64 + ni * 16 + c][g * 8];
#pragma unroll
        for (int mi = 0; mi < 4; ++mi)
#pragma unroll
            for (int ni = 0; ni < 4; ++ni)
                acc[mi][ni] = __builtin_amdgcn_mfma_f32_16x16x32_f16(
                    af[mi], bf[ni], acc[mi][ni], 0, 0, 0);

        // ---- commit prefetched tile to the other buffer ----
        if (pf) {
            _Float16 (*An)[40] = (_Float16(*)[40])(smem + (cur ^ 1u) * 20480);
            _Float16 (*Bn)[40] = (_Float16(*)[40])(smem + (cur ^ 1u) * 20480 + 10240);
            if (A_F16) {
                *(half8*)&An[srow][skh]     = av0;
                *(half8*)&An[srow][skh + 8] = av1;
            } else {
                half8 a0 = { (_Float16)pv0.x, (_Float16)pv0.y, (_Float16)pv0.z, (_Float16)pv0.w,
                             (_Float16)pv1.x, (_Float16)pv1.y, (_Float16)pv1.z, (_Float16)pv1.w };
                half8 a1 = { (_Float16)pv2.x, (_Float16)pv2.y, (_Float16)pv2.z, (_Float16)pv2.w,
                             (_Float16)pv3.x, (_Float16)pv3.y, (_Float16)pv3.z, (_Float16)pv3.w };
                *(half8*)&An[srow][skh]     = a0;
                *(half8*)&An[srow][skh + 8] = a1;
            }
            *(half8*)&Bn[srow][skh]     = bv0;
            *(half8*)&Bn[srow][skh + 8] = bv1;
            __syncthreads();
        }
    }

    // ---- LDS-staged coalesced epilogue (reuses buffer 0; last tile was buffer 1) ----
    // acc[mi][ni][r] = C[m0 + wm*64 + mi*16 + 4g + r][n0 + wn*64 + ni*16 + c]
    if (OUT_F16) {
        _Float16 (*C16)[68] = (_Float16(*)[68])smem;   // 128x68 halves = 17408 B
#pragma unroll
        for (int p = 0; p < 2; ++p) {
            __syncthreads();
            if (wn == p) {
#pragma unroll
                for (int ni = 0; ni < 4; ++ni) {
                    const float bv = bias[n0 + p * 64 + ni * 16 + c];
#pragma unroll
                    for (int mi = 0; mi < 4; ++mi)
#pragma unroll
                        for (int r = 0; r < 4; ++r) {
                            float v = acc[mi][ni][r] + bv;
                            if (EPI == EPI_GELU) v = gelu_f(v);
                            C16[wm * 64 + mi * 16 + 4 * g + r][ni * 16 + c] = (_Float16)v;
                        }
                }
            }
            __syncthreads();
            const int row = tid >> 1, coff = (tid & 1) * 32;
            _Float16* dst = (_Float16*)outp + (size_t)(m0 + row) * Nout + n0 + p * 64 + coff;
#pragma unroll
            for (int jj = 0; jj < 4; ++jj)
                *(half8*)&dst[jj * 8] = *(const half8*)&C16[row][coff + jj * 8];
        }
    } else {
        float (*C32)[33] = (float(*)[33])smem;         // 128x33 floats = 16896 B
#pragma unroll
        for (int p2 = 0; p2 < 4; ++p2) {
            __syncthreads();
            if (wn == (p2 >> 1)) {
#pragma unroll
                for (int q = 0; q < 2; ++q) {
                    const int ni = (p2 & 1) * 2 + q;
                    const float bv = bias[n0 + wn * 64 + ni * 16 + c];
#pragma unroll
                    for (int mi = 0; mi < 4; ++mi)
#pragma unroll
                        for (int r = 0; r < 4; ++r)
                            C32[wm * 64 + mi * 16 + 4 * g + r][q * 16 + c] =
                                acc[mi][ni][r] + bv;
                }
            }
            __syncthreads();
            const int row = tid >> 1, c0 = (tid & 1) * 16;
            const int gcol = n0 + (p2 >> 1) * 64 + (p2 & 1) * 32 + c0;
            float* dst = (float*)outp + (size_t)(m0 + row) * Nout + gcol;
            const float* rsd = (EPI == EPI_RES)
                                   ? &resid[(size_t)(m0 + row) * Nout + gcol]
                                   : nullptr;
#pragma unroll
            for (int jj = 0; jj < 4; ++jj) {
                float4 v = *(const float4*)&C32[row][c0 + jj * 4];
                if (EPI == EPI_RES) {
                    float4 rv = *(const float4*)&rsd[jj * 4];
                    v.x += rv.x; v.y += rv.y; v.z += rv.z; v.w += rv.w;
                }
                *(float4*)&dst[jj * 4] = v;
            }
        }
    }
}

// ---------------- MFMA windowed causal attention ----------------
__global__ __launch_bounds__(256) void k_attn_mfma(const _Float16* __restrict__ qkv,
                                                   _Float16* __restrict__ ctx) {
    __shared__ _Float16 Vt[32][200];   // V^T: [dim][key]
    __shared__ _Float16 Pl[64][200];   // P:   [query][key]
    const int qt = blockIdx.x;
    const int nh = blockIdx.y;
    const int n = nh >> 3, h = nh & 7;     // group-local sequence
    const int q0 = qt * 64;
    const int jlo = (q0 >= WLEN - 1) ? (q0 - (WLEN - 1)) : 0;
    const int tid = threadIdx.x;
    const int w = tid >> 6;
    const int lane = tid & 63;
    const int g = lane >> 4, c = lane & 15;
    const size_t base = (size_t)n * T_ * (3 * C_);
    const int hq = h * DH;

    for (int idx = tid; idx < 192 * 4; idx += 256) {
        int rj = idx >> 2, dp = (idx & 3) * 8;
        int vr = jlo + rj; if (vr > T_ - 1) vr = T_ - 1;
        half8 vv = *(const half8*)&qkv[base + (size_t)vr * (3 * C_) + 2 * C_ + hq + dp];
#pragma unroll
        for (int u = 0; u < 8; ++u) Vt[dp + u][rj] = vv[u];
    }

    half8 qf = *(const half8*)&qkv[base + (size_t)(q0 + w * 16 + c) * (3 * C_) + hq + g * 8];

    f32x4 s[12];
#pragma unroll
    for (int t = 0; t < 12; ++t) {
        int jr = jlo + 16 * t + c; if (jr > T_ - 1) jr = T_ - 1;
        half8 kf = *(const half8*)&qkv[base + (size_t)jr * (3 * C_) + C_ + hq + g * 8];
        f32x4 z = {0.f, 0.f, 0.f, 0.f};
        s[t] = __builtin_amdgcn_mfma_f32_16x16x32_f16(qf, kf, z, 0, 0, 0);
    }

    const float scale = 0.17677669529663687f;   // 1/sqrt(32)
    float invl[4];
#pragma unroll
    for (int r = 0; r < 4; ++r) {
        const int i = q0 + w * 16 + 4 * g + r;
        float m = -3.0e38f;
        float sv[12];
#pragma unroll
        for (int t = 0; t < 12; ++t) {
            int j = jlo + 16 * t + c;
            bool ok = (j <= i) && (j > i - WLEN);
            float v = ok ? s[t][r] * scale : -3.0e38f;
            sv[t] = v;
            m = fmaxf(m, v);
        }
        m = fmaxf(m, __shfl_xor(m, 1));
        m = fmaxf(m, __shfl_xor(m, 2));
        m = fmaxf(m, __shfl_xor(m, 4));
        m = fmaxf(m, __shfl_xor(m, 8));
        float l = 0.f;
#pragma unroll
        for (int t = 0; t < 12; ++t) {
            float p = (sv[t] > -1.0e38f) ? __expf(sv[t] - m) : 0.f;
            l += p;
            Pl[w * 16 + 4 * g + r][16 * t + c] = (_Float16)p;
        }
        l += __shfl_xor(l, 1);
        l += __shfl_xor(l, 2);
        l += __shfl_xor(l, 4);
        l += __shfl_xor(l, 8);
        invl[r] = 1.0f / l;
    }
    __syncthreads();

    f32x4 o0 = {0.f, 0.f, 0.f, 0.f}, o1 = {0.f, 0.f, 0.f, 0.f};
#pragma unroll
    for (int ks = 0; ks < 6; ++ks) {
        half8 pa = *(const half8*)&Pl[w * 16 + c][32 * ks + 8 * g];
        half8 b0 = *(const half8*)&Vt[c][32 * ks + 8 * g];
        half8 b1 = *(const half8*)&Vt[c + 16][32 * ks + 8 * g];
        o0 = __builtin_amdgcn_mfma_f32_16x16x32_f16(pa, b0, o0, 0, 0, 0);
        o1 = __builtin_amdgcn_mfma_f32_16x16x32_f16(pa, b1, o1, 0, 0, 0);
    }
#pragma unroll
    for (int r = 0; r < 4; ++r) {
        const int i = q0 + w * 16 + 4 * g + r;
        _Float16* op = &ctx[((size_t)n * T_ + i) * C_ + hq];
        op[c]      = (_Float16)(o0[r] * invl[r]);
        op[c + 16] = (_Float16)(o1[r] * invl[r]);
    }
}

// ---------------- LayerNorm over last dim C=256; one wave per row ----------------
__global__ __launch_bounds__(256) void k_ln(const float* __restrict__ in,
                                            const float* __restrict__ g,
                                            const float* __restrict__ b,
                                            float* __restrict__ out) {
    const int row = blockIdx.x * 4 + (threadIdx.x >> 6);
    const int lane = threadIdx.x & 63;
    const float4 v = *(const float4*)&in[(size_t)row * C_ + lane * 4];
    float s = v.x + v.y + v.z + v.w;
    float sq = v.x * v.x + v.y * v.y + v.z * v.z + v.w * v.w;
#pragma unroll
    for (int off = 1; off < 64; off <<= 1) {
        s += __shfl_xor(s, off);
        sq += __shfl_xor(sq, off);
    }
    float mu = s * (1.0f / C_);
    float var = sq * (1.0f / C_) - mu * mu;
    if (var < 0.f) var = 0.f;
    float rstd = rsqrtf(var + 1e-5f);
    float4 gv = *(const float4*)&g[lane * 4];
    float4 bv = *(const float4*)&b[lane * 4];
    float4 o;
    o.x = (v.x - mu) * rstd * gv.x + bv.x;
    o.y = (v.y - mu) * rstd * gv.y + bv.y;
    o.z = (v.z - mu) * rstd * gv.z + bv.z;
    o.w = (v.w - mu) * rstd * gv.w + bv.w;
    *(float4*)&out[(size_t)row * C_ + lane * 4] = o;
}

// ---------------- launch ----------------
extern "C" void kernel_launch(void* const* d_in, const int* in_sizes, int n_in,
                              void* d_out, int out_size, void* d_ws, size_t ws_size,
                              hipStream_t stream) {
    (void)in_sizes; (void)n_in; (void)out_size;
    const float* x     = (const float*)d_in[0];
    const float* in_w  = (const float*)d_in[1];
    const float* in_b  = (const float*)d_in[2];
    const float* out_w = (const float*)d_in[3];
    const float* out_b = (const float*)d_in[4];
    const float* ln1g  = (const float*)d_in[5];
    const float* ln1b  = (const float*)d_in[6];
    const float* w1    = (const float*)d_in[7];
    const float* b1    = (const float*)d_in[8];
    const float* w2    = (const float*)d_in[9];
    const float* b2    = (const float*)d_in[10];
    const float* ln2g  = (const float*)d_in[11];
    const float* ln2b  = (const float*)d_in[12];
    float* out = (float*)d_out;
    float* ws  = (float*)d_ws;

    // Workspace (floats):
    //   A  = [0, NTC)       : xs, then nrm (after LN1)
    //   B  = [NTC, 2NTC)    : qkv16 (fp16) -> res1 -> tmp2
    //   C  = [2NTC, ...)    : h16 (fp16), then W16 tail
    // ctx16 / res2 live in d_out.
    const int G = (ws_size >= (size_t)3 * NTC * sizeof(float)) ? 4 : 8;
    const int Ng = N_ / G;
    const long long Mg = (long long)Ng * T_;

    float* xs   = ws;
    float* nrm  = ws;
    _Float16* qkv16 = (_Float16*)(ws + NTC);
    float* res1 = ws + NTC;
    float* tmp2 = ws + NTC;
    _Float16* h16 = (_Float16*)(ws + 2 * NTC);
    float* wtail = ws + 2 * NTC + (size_t)Mg * 512;
    _Float16* w16_in  = (_Float16*)wtail;           // 196608
    _Float16* w16_out = w16_in + 196608;            // 65536
    _Float16* w16_1   = w16_out + 65536;            // 262144
    _Float16* w16_2   = w16_1 + 262144;             // 262144
    _Float16* ctx16 = (_Float16*)d_out;             // d_out as scratch (fp16)
    float* res2 = out;                              // d_out as scratch (fp32)

    // weight conversion
    k_cvt16<<<192, 256, 0, stream>>>(in_w,  w16_in,  196608 / 4);
    k_cvt16<<<64,  256, 0, stream>>>(out_w, w16_out, 65536 / 4);
    k_cvt16<<<256, 256, 0, stream>>>(w1,    w16_1,   262144 / 4);
    k_cvt16<<<256, 256, 0, stream>>>(w2,    w16_2,   262144 / 4);

    dim3 tb(32, 8);
    k_transpose_in<<<dim3(C_ / 32, F_ / 32, B_ * T_), tb, 0, stream>>>(x, xs);

    // QKV projection + attention, per sequence-group
    for (int g = 0; g < G; ++g) {
        const float* xs_g = xs + (size_t)g * Mg * C_;
        k_gemm_mfma<EPI_NONE, false, true><<<dim3(768 / 128, Mg / 128), 256, 0, stream>>>(
            xs_g, w16_in, in_b, nullptr, qkv16, 3 * C_, C_);
        k_attn_mfma<<<dim3(T_ / 64, Ng * H_), 256, 0, stream>>>(
            qkv16, ctx16 + (size_t)g * Mg * C_);
    }

    // out projection + residual(xs), full M (A = fp16 ctx)
    k_gemm_mfma<EPI_RES, true, false><<<dim3(C_ / 128, M_ / 128), 256, 0, stream>>>(
        ctx16, w16_out, out_b, xs, res1, C_, C_);

    // LN1: res1 -> nrm
    k_ln<<<M_ / 4, 256, 0, stream>>>(res1, ln1g, ln1b, nrm);

    // FFN per row-group
    for (int g = 0; g < G; ++g) {
        const float* nrm_g = nrm + (size_t)g * Mg * C_;
        k_gemm_mfma<EPI_GELU, false, true><<<dim3(FF / 128, Mg / 128), 256, 0, stream>>>(
            nrm_g, w16_1, b1, nullptr, h16, FF, C_);
        k_gemm_mfma<EPI_RES, true, false><<<dim3(C_ / 128, Mg / 128), 256, 0, stream>>>(
            h16, w16_2, b2, nrm_g, res2 + (size_t)g * Mg * C_, C_, FF);
    }

    // LN2: res2(d_out) -> tmp2
    k_ln<<<M_ / 4, 256, 0, stream>>>(res2, ln2g, ln2b, tmp2);

    // back to (B,C,T,F)
    k_transpose_out<<<dim3(C_ / 32, F_ / 32, B_ * T_), tb, 0, stream>>>(tmp2, out);
}

// Round 9
// 560.870 us; speedup vs baseline: 1.3613x; 1.2772x over previous
//
#include <hip/hip_runtime.h>
#include <cmath>

// ---------------- problem constants ----------------
constexpr int B_  = 2;
constexpr int C_  = 256;   // NDIM
constexpr int T_  = 512;
constexpr int F_  = 64;
constexpr int N_  = B_ * F_;     // 128 sequences
constexpr int H_  = 8;
constexpr int DH  = 32;          // head dim
constexpr int FF  = 1024;        // R*NDIM
constexpr int WLEN = 128;
constexpr int M_  = N_ * T_;     // 65536 rows
constexpr long long NTC = (long long)N_ * T_ * C_;  // 16777216 elements

typedef _Float16 half8 __attribute__((ext_vector_type(8)));
typedef _Float16 half4v __attribute__((ext_vector_type(4)));
typedef float f32x4 __attribute__((ext_vector_type(4)));

// ---------------- fp32 -> fp16 convert (weights) ----------------
__global__ __launch_bounds__(256) void k_cvt16(const float* __restrict__ in,
                                               _Float16* __restrict__ out, int n4) {
    int i = blockIdx.x * 256 + threadIdx.x;
    if (i < n4) {
        float4 v = ((const float4*)in)[i];
        half4v h = { (_Float16)v.x, (_Float16)v.y, (_Float16)v.z, (_Float16)v.w };
        *(half4v*)&out[(size_t)i * 4] = h;
    }
}

// ---------------- transpose in: x (B,C,T,F) -> xs (N=B*F, T, C) ----------------
__global__ __launch_bounds__(256) void k_transpose_in(const float* __restrict__ x,
                                                      float* __restrict__ xs) {
    __shared__ float tile[32][33];
    const int bz = blockIdx.z;            // b*T + t
    const int b = bz >> 9, t = bz & 511;
    const int c0 = blockIdx.x * 32, f0 = blockIdx.y * 32;
    const int tx = threadIdx.x, ty = threadIdx.y;   // 32 x 8
#pragma unroll
    for (int i = 0; i < 4; ++i) {
        int c = c0 + ty + i * 8;
        tile[ty + i * 8][tx] = x[(((size_t)(b * C_ + c)) * T_ + t) * F_ + f0 + tx];
    }
    __syncthreads();
#pragma unroll
    for (int i = 0; i < 4; ++i) {
        int f = f0 + ty + i * 8;
        xs[(((size_t)(b * F_ + f)) * T_ + t) * C_ + c0 + tx] = tile[tx][ty + i * 8];
    }
}

// ---------------- transpose out: tmp (N,T,C) -> out (B,C,T,F) ----------------
__global__ __launch_bounds__(256) void k_transpose_out(const float* __restrict__ tmp,
                                                       float* __restrict__ out) {
    __shared__ float tile[32][33];
    const int bz = blockIdx.z;
    const int b = bz >> 9, t = bz & 511;
    const int c0 = blockIdx.x * 32, f0 = blockIdx.y * 32;
    const int tx = threadIdx.x, ty = threadIdx.y;
#pragma unroll
    for (int i = 0; i < 4; ++i) {
        int f = f0 + ty + i * 8;
        tile[ty + i * 8][tx] = tmp[(((size_t)(b * F_ + f)) * T_ + t) * C_ + c0 + tx];
    }
    __syncthreads();
#pragma unroll
    for (int i = 0; i < 4; ++i) {
        int c = c0 + ty + i * 8;
        out[(((size_t)(b * C_ + c)) * T_ + t) * F_ + f0 + tx] = tile[tx][ty + i * 8];
    }
}

// ---------------- MFMA GEMM: out[m][n] = sum_k A[m][k]*W[n][k] + bias[n] ----------------
enum { EPI_NONE = 0, EPI_RES = 1, EPI_GELU = 2 };

__device__ __forceinline__ float gelu_f(float v) {
    return 0.5f * v * (1.0f + erff(v * 0.70710678118654752f));
}

// BM=64, BN=128, BK=32. 256 threads = 4 waves (2x2), wave tile 32x64 via 2x4
// 16x16x32 MFMA frags. Double-buffered LDS (30KB -> 5 blocks/CU), register
// prefetch, XCD-chunked block swizzle, LDS-staged coalesced epilogue.
// Requires gridDim.y % 8 == 0 and K % 64 == 0.
template <int EPI, bool A_F16, bool OUT_F16>
__global__ __launch_bounds__(256) void k_gemm_mfma(const void* __restrict__ Aptr,
                                                   const _Float16* __restrict__ W,
                                                   const float* __restrict__ bias,
                                                   const float* __restrict__ resid,
                                                   void* __restrict__ outp,
                                                   int Nout, int K) {
    __shared__ __align__(16) unsigned char smem[30720];  // 2 x (As 5120 + Bs 10240)

    // ---- XCD-chunked block swizzle ----
    const int nx = gridDim.x;
    const int flat = blockIdx.x + nx * blockIdx.y;   // HW dispatch order (x fastest)
    const int xcd = flat & 7;
    const int s = flat >> 3;
    const int mpx = gridDim.y >> 3;                  // m-tiles per XCD
    const int n0 = (s % nx) * 128;
    const int m0 = (xcd * mpx + s / nx) * 64;

    const int tid  = threadIdx.x;
    const int lane = tid & 63;
    const int wid  = tid >> 6;
    const int wm = wid >> 1, wn = wid & 1;
    const int g = lane >> 4, c = lane & 15;
    const int arow = tid >> 2, ask = (tid & 3) * 8;   // A stage: 64 rows x 32 halves
    const int brow = tid >> 1, bsk = (tid & 1) * 16;  // B stage: 128 rows x 32 halves

    const char* abase = (const char*)Aptr +
        (A_F16 ? ((size_t)(m0 + arow) * K + ask) * 2
               : ((size_t)(m0 + arow) * K + ask) * 4);
    const _Float16* bbase = W + (size_t)(n0 + brow) * K + bsk;

    f32x4 acc[2][4] = {};

    // ---- prologue: stage tile 0 into buffer 0 ----
    {
        _Float16 (*As)[40] = (_Float16(*)[40])(smem);
        _Float16 (*Bs)[40] = (_Float16(*)[40])(smem + 5120);
        if (A_F16) {
            *(half8*)&As[arow][ask] = *(const half8*)abase;
        } else {
            const float4* ap = (const float4*)abase;
            float4 v0 = ap[0], v1 = ap[1];
            half8 a0 = { (_Float16)v0.x, (_Float16)v0.y, (_Float16)v0.z, (_Float16)v0.w,
                         (_Float16)v1.x, (_Float16)v1.y, (_Float16)v1.z, (_Float16)v1.w };
            *(half8*)&As[arow][ask] = a0;
        }
        const half8* bp = (const half8*)bbase;
        *(half8*)&Bs[brow][bsk]     = bp[0];
        *(half8*)&Bs[brow][bsk + 8] = bp[1];
    }
    __syncthreads();

    const int nt = K >> 5;
    float4 pv0, pv1;
    half8 av0, bv0, bv1;

    for (int t = 0; t < nt; ++t) {
        const unsigned cur = (unsigned)t & 1u;
        _Float16 (*As)[40] = (_Float16(*)[40])(smem + cur * 15360);
        _Float16 (*Bs)[40] = (_Float16(*)[40])(smem + cur * 15360 + 5120);
        const bool pf = (t + 1 < nt);

        // ---- issue next tile's global loads (in flight across MFMAs) ----
        if (pf) {
            const int k0 = (t + 1) << 5;
            if (A_F16) {
                av0 = *(const half8*)(abase + (size_t)k0 * 2);
            } else {
                const float4* ap = (const float4*)(abase + (size_t)k0 * 4);
                pv0 = ap[0]; pv1 = ap[1];
            }
            const half8* bp = (const half8*)(bbase + k0);
            bv0 = bp[0]; bv1 = bp[1];
        }

        // ---- compute current tile ----
        half8 af[2], bf[4];
#pragma unroll
        for (int mi = 0; mi < 2; ++mi)
            af[mi] = *(const half8*)&As[wm * 32 + mi * 16 + c][g * 8];
#pragma unroll
        for (int ni = 0; ni < 4; ++ni)
            bf[ni] = *(const half8*)&Bs[wn * 64 + ni * 16 + c][g * 8];
#pragma unroll
        for (int mi = 0; mi < 2; ++mi)
#pragma unroll
            for (int ni = 0; ni < 4; ++ni)
                acc[mi][ni] = __builtin_amdgcn_mfma_f32_16x16x32_f16(
                    af[mi], bf[ni], acc[mi][ni], 0, 0, 0);

        // ---- commit prefetched tile to the other buffer ----
        if (pf) {
            _Float16 (*An)[40] = (_Float16(*)[40])(smem + (cur ^ 1u) * 15360);
            _Float16 (*Bn)[40] = (_Float16(*)[40])(smem + (cur ^ 1u) * 15360 + 5120);
            if (A_F16) {
                *(half8*)&An[arow][ask] = av0;
            } else {
                half8 a0 = { (_Float16)pv0.x, (_Float16)pv0.y, (_Float16)pv0.z, (_Float16)pv0.w,
                             (_Float16)pv1.x, (_Float16)pv1.y, (_Float16)pv1.z, (_Float16)pv1.w };
                *(half8*)&An[arow][ask] = a0;
            }
            *(half8*)&Bn[brow][bsk]     = bv0;
            *(half8*)&Bn[brow][bsk + 8] = bv1;
            __syncthreads();
        }
    }

    // ---- LDS-staged coalesced epilogue ----
    // acc[mi][ni][r] = C[m0 + wm*32 + mi*16 + 4g + r][n0 + wn*64 + ni*16 + c]
    if (OUT_F16) {
        _Float16 (*C16)[68] = (_Float16(*)[68])smem;   // 64x68 halves = 8704 B
#pragma unroll
        for (int p = 0; p < 2; ++p) {
            __syncthreads();
            if (wn == p) {
#pragma unroll
                for (int ni = 0; ni < 4; ++ni) {
                    const float bv = bias[n0 + p * 64 + ni * 16 + c];
#pragma unroll
                    for (int mi = 0; mi < 2; ++mi)
#pragma unroll
                        for (int r = 0; r < 4; ++r) {
                            float v = acc[mi][ni][r] + bv;
                            if (EPI == EPI_GELU) v = gelu_f(v);
                            C16[wm * 32 + mi * 16 + 4 * g + r][ni * 16 + c] = (_Float16)v;
                        }
                }
            }
            __syncthreads();
            const int row = tid >> 2, coff = (tid & 3) * 16;
            _Float16* dst = (_Float16*)outp + (size_t)(m0 + row) * Nout + n0 + p * 64 + coff;
            *(half8*)&dst[0] = *(const half8*)&C16[row][coff];
            *(half8*)&dst[8] = *(const half8*)&C16[row][coff + 8];
        }
    } else {
        float (*C32)[33] = (float(*)[33])smem;         // 64x33 floats = 8448 B
#pragma unroll
        for (int p2 = 0; p2 < 4; ++p2) {
            __syncthreads();
            if (wn == (p2 >> 1)) {
#pragma unroll
                for (int q = 0; q < 2; ++q) {
                    const int ni = (p2 & 1) * 2 + q;
                    const float bv = bias[n0 + wn * 64 + ni * 16 + c];
#pragma unroll
                    for (int mi = 0; mi < 2; ++mi)
#pragma unroll
                        for (int r = 0; r < 4; ++r)
                            C32[wm * 32 + mi * 16 + 4 * g + r][q * 16 + c] =
                                acc[mi][ni][r] + bv;
                }
            }
            __syncthreads();
            const int row = tid >> 2, c0 = (tid & 3) * 8;
            const int gcol = n0 + (p2 >> 1) * 64 + (p2 & 1) * 32 + c0;
            float* dst = (float*)outp + (size_t)(m0 + row) * Nout + gcol;
            const float* rsd = (EPI == EPI_RES)
                                   ? &resid[(size_t)(m0 + row) * Nout + gcol]
                                   : nullptr;
#pragma unroll
            for (int jj = 0; jj < 2; ++jj) {
                float4 v = *(const float4*)&C32[row][c0 + jj * 4];
                if (EPI == EPI_RES) {
                    float4 rv = *(const float4*)&rsd[jj * 4];
                    v.x += rv.x; v.y += rv.y; v.z += rv.z; v.w += rv.w;
                }
                *(float4*)&dst[jj * 4] = v;
            }
        }
    }
}

// ---------------- MFMA windowed causal attention ----------------
__global__ __launch_bounds__(256) void k_attn_mfma(const _Float16* __restrict__ qkv,
                                                   _Float16* __restrict__ ctx) {
    __shared__ _Float16 Vt[32][200];   // V^T: [dim][key]
    __shared__ _Float16 Pl[64][200];   // P:   [query][key]
    const int qt = blockIdx.x;
    const int nh = blockIdx.y;
    const int n = nh >> 3, h = nh & 7;
    const int q0 = qt * 64;
    const int jlo = (q0 >= WLEN - 1) ? (q0 - (WLEN - 1)) : 0;
    const int tid = threadIdx.x;
    const int w = tid >> 6;
    const int lane = tid & 63;
    const int g = lane >> 4, c = lane & 15;
    const size_t base = (size_t)n * T_ * (3 * C_);
    const int hq = h * DH;

    for (int idx = tid; idx < 192 * 4; idx += 256) {
        int rj = idx >> 2, dp = (idx & 3) * 8;
        int vr = jlo + rj; if (vr > T_ - 1) vr = T_ - 1;
        half8 vv = *(const half8*)&qkv[base + (size_t)vr * (3 * C_) + 2 * C_ + hq + dp];
#pragma unroll
        for (int u = 0; u < 8; ++u) Vt[dp + u][rj] = vv[u];
    }

    half8 qf = *(const half8*)&qkv[base + (size_t)(q0 + w * 16 + c) * (3 * C_) + hq + g * 8];

    f32x4 s[12];
#pragma unroll
    for (int t = 0; t < 12; ++t) {
        int jr = jlo + 16 * t + c; if (jr > T_ - 1) jr = T_ - 1;
        half8 kf = *(const half8*)&qkv[base + (size_t)jr * (3 * C_) + C_ + hq + g * 8];
        f32x4 z = {0.f, 0.f, 0.f, 0.f};
        s[t] = __builtin_amdgcn_mfma_f32_16x16x32_f16(qf, kf, z, 0, 0, 0);
    }

    const float scale = 0.17677669529663687f;   // 1/sqrt(32)
    float invl[4];
#pragma unroll
    for (int r = 0; r < 4; ++r) {
        const int i = q0 + w * 16 + 4 * g + r;
        float m = -3.0e38f;
        float sv[12];
#pragma unroll
        for (int t = 0; t < 12; ++t) {
            int j = jlo + 16 * t + c;
            bool ok = (j <= i) && (j > i - WLEN);
            float v = ok ? s[t][r] * scale : -3.0e38f;
            sv[t] = v;
            m = fmaxf(m, v);
        }
        m = fmaxf(m, __shfl_xor(m, 1));
        m = fmaxf(m, __shfl_xor(m, 2));
        m = fmaxf(m, __shfl_xor(m, 4));
        m = fmaxf(m, __shfl_xor(m, 8));
        float l = 0.f;
#pragma unroll
        for (int t = 0; t < 12; ++t) {
            float p = (sv[t] > -1.0e38f) ? __expf(sv[t] - m) : 0.f;
            l += p;
            Pl[w * 16 + 4 * g + r][16 * t + c] = (_Float16)p;
        }
        l += __shfl_xor(l, 1);
        l += __shfl_xor(l, 2);
        l += __shfl_xor(l, 4);
        l += __shfl_xor(l, 8);
        invl[r] = 1.0f / l;
    }
    __syncthreads();

    f32x4 o0 = {0.f, 0.f, 0.f, 0.f}, o1 = {0.f, 0.f, 0.f, 0.f};
#pragma unroll
    for (int ks = 0; ks < 6; ++ks) {
        half8 pa = *(const half8*)&Pl[w * 16 + c][32 * ks + 8 * g];
        half8 b0 = *(const half8*)&Vt[c][32 * ks + 8 * g];
        half8 b1 = *(const half8*)&Vt[c + 16][32 * ks + 8 * g];
        o0 = __builtin_amdgcn_mfma_f32_16x16x32_f16(pa, b0, o0, 0, 0, 0);
        o1 = __builtin_amdgcn_mfma_f32_16x16x32_f16(pa, b1, o1, 0, 0, 0);
    }
#pragma unroll
    for (int r = 0; r < 4; ++r) {
        const int i = q0 + w * 16 + 4 * g + r;
        _Float16* op = &ctx[((size_t)n * T_ + i) * C_ + hq];
        op[c]      = (_Float16)(o0[r] * invl[r]);
        op[c + 16] = (_Float16)(o1[r] * invl[r]);
    }
}

// ---------------- LayerNorm over last dim C=256; one wave per row ----------------
__global__ __launch_bounds__(256) void k_ln(const float* __restrict__ in,
                                            const float* __restrict__ g,
                                            const float* __restrict__ b,
                                            float* __restrict__ out) {
    const int row = blockIdx.x * 4 + (threadIdx.x >> 6);
    const int lane = threadIdx.x & 63;
    const float4 v = *(const float4*)&in[(size_t)row * C_ + lane * 4];
    float s = v.x + v.y + v.z + v.w;
    float sq = v.x * v.x + v.y * v.y + v.z * v.z + v.w * v.w;
#pragma unroll
    for (int off = 1; off < 64; off <<= 1) {
        s += __shfl_xor(s, off);
        sq += __shfl_xor(sq, off);
    }
    float mu = s * (1.0f / C_);
    float var = sq * (1.0f / C_) - mu * mu;
    if (var < 0.f) var = 0.f;
    float rstd = rsqrtf(var + 1e-5f);
    float4 gv = *(const float4*)&g[lane * 4];
    float4 bv = *(const float4*)&b[lane * 4];
    float4 o;
    o.x = (v.x - mu) * rstd * gv.x + bv.x;
    o.y = (v.y - mu) * rstd * gv.y + bv.y;
    o.z = (v.z - mu) * rstd * gv.z + bv.z;
    o.w = (v.w - mu) * rstd * gv.w + bv.w;
    *(float4*)&out[(size_t)row * C_ + lane * 4] = o;
}

// ---------------- launch ----------------
extern "C" void kernel_launch(void* const* d_in, const int* in_sizes, int n_in,
                              void* d_out, int out_size, void* d_ws, size_t ws_size,
                              hipStream_t stream) {
    (void)in_sizes; (void)n_in; (void)out_size;
    const float* x     = (const float*)d_in[0];
    const float* in_w  = (const float*)d_in[1];
    const float* in_b  = (const float*)d_in[2];
    const float* out_w = (const float*)d_in[3];
    const float* out_b = (const float*)d_in[4];
    const float* ln1g  = (const float*)d_in[5];
    const float* ln1b  = (const float*)d_in[6];
    const float* w1    = (const float*)d_in[7];
    const float* b1    = (const float*)d_in[8];
    const float* w2    = (const float*)d_in[9];
    const float* b2    = (const float*)d_in[10];
    const float* ln2g  = (const float*)d_in[11];
    const float* ln2b  = (const float*)d_in[12];
    float* out = (float*)d_out;
    float* ws  = (float*)d_ws;

    _Float16* ctx16 = (_Float16*)d_out;   // d_out as scratch (fp16)
    float* res2 = out;                    // d_out as scratch (fp32)
    dim3 tb(32, 8);

    // Full-M layout needs 2.5*NTC + weights = 42,336,256 floats (169.3 MiB).
    const bool fullM = ws_size >= (size_t)42336256 * 4;

    if (fullM) {
        // [0,NTC): xs -> nrm. [NTC,2.5NTC): qkv16; later res1/h16/tmp2 in [NTC,2NTC).
        // [2.5NTC, +1.5MiB): fp16 weights.
        float* xs   = ws;
        float* nrm  = ws;
        _Float16* qkv16 = (_Float16*)(ws + NTC);
        float* res1 = ws + NTC;
        float* tmp2 = ws + NTC;
        _Float16* h16 = (_Float16*)(ws + NTC);
        _Float16* w16_in  = (_Float16*)(ws + (size_t)41943040);
        _Float16* w16_out = w16_in + 196608;
        _Float16* w16_1   = w16_out + 65536;
        _Float16* w16_2   = w16_1 + 262144;
        const long long Mg2 = M_ / 2;

        k_cvt16<<<192, 256, 0, stream>>>(in_w,  w16_in,  196608 / 4);
        k_cvt16<<<64,  256, 0, stream>>>(out_w, w16_out, 65536 / 4);
        k_cvt16<<<256, 256, 0, stream>>>(w1,    w16_1,   262144 / 4);
        k_cvt16<<<256, 256, 0, stream>>>(w2,    w16_2,   262144 / 4);

        k_transpose_in<<<dim3(C_ / 32, F_ / 32, B_ * T_), tb, 0, stream>>>(x, xs);

        // QKV projection, full M (grid 6 x 1024)
        k_gemm_mfma<EPI_NONE, false, true><<<dim3(6, M_ / 64), 256, 0, stream>>>(
            xs, w16_in, in_b, nullptr, qkv16, 3 * C_, C_);
        // attention, full (grid 8 x 1024)
        k_attn_mfma<<<dim3(T_ / 64, N_ * H_), 256, 0, stream>>>(qkv16, ctx16);
        // out projection + residual(xs), full M
        k_gemm_mfma<EPI_RES, true, false><<<dim3(2, M_ / 64), 256, 0, stream>>>(
            ctx16, w16_out, out_b, xs, res1, C_, C_);
        // LN1
        k_ln<<<M_ / 4, 256, 0, stream>>>(res1, ln1g, ln1b, nrm);
        // FFN in 2 halves (h16 buffer reuse)
        for (int g = 0; g < 2; ++g) {
            const float* nrm_g = nrm + (size_t)g * Mg2 * C_;
            k_gemm_mfma<EPI_GELU, false, true><<<dim3(8, Mg2 / 64), 256, 0, stream>>>(
                nrm_g, w16_1, b1, nullptr, h16, FF, C_);
            k_gemm_mfma<EPI_RES, true, false><<<dim3(2, Mg2 / 64), 256, 0, stream>>>(
                h16, w16_2, b2, nrm_g, res2 + (size_t)g * Mg2 * C_, C_, FF);
        }
        // LN2
        k_ln<<<M_ / 4, 256, 0, stream>>>(res2, ln2g, ln2b, tmp2);
        k_transpose_out<<<dim3(C_ / 32, F_ / 32, B_ * T_), tb, 0, stream>>>(tmp2, out);
    } else {
        // Fallback: G=8 chunked (peak ~152 MiB), proven-safe layout.
        const int G = 8;
        const int Ng = N_ / G;
        const long long Mg = (long long)Ng * T_;
        float* xs   = ws;
        float* nrm  = ws;
        _Float16* qkv16 = (_Float16*)(ws + NTC);
        float* res1 = ws + NTC;
        float* tmp2 = ws + NTC;
        _Float16* h16 = (_Float16*)(ws + 2 * NTC);
        float* wtail = ws + 2 * NTC + (size_t)Mg * 512;
        _Float16* w16_in  = (_Float16*)wtail;
        _Float16* w16_out = w16_in + 196608;
        _Float16* w16_1   = w16_out + 65536;
        _Float16* w16_2   = w16_1 + 262144;

        k_cvt16<<<192, 256, 0, stream>>>(in_w,  w16_in,  196608 / 4);
        k_cvt16<<<64,  256, 0, stream>>>(out_w, w16_out, 65536 / 4);
        k_cvt16<<<256, 256, 0, stream>>>(w1,    w16_1,   262144 / 4);
        k_cvt16<<<256, 256, 0, stream>>>(w2,    w16_2,   262144 / 4);

        k_transpose_in<<<dim3(C_ / 32, F_ / 32, B_ * T_), tb, 0, stream>>>(x, xs);

        for (int g = 0; g < G; ++g) {
            const float* xs_g = xs + (size_t)g * Mg * C_;
            k_gemm_mfma<EPI_NONE, false, true><<<dim3(6, Mg / 64), 256, 0, stream>>>(
                xs_g, w16_in, in_b, nullptr, qkv16, 3 * C_, C_);
            k_attn_mfma<<<dim3(T_ / 64, Ng * H_), 256, 0, stream>>>(
                qkv16, ctx16 + (size_t)g * Mg * C_);
        }
        k_gemm_mfma<EPI_RES, true, false><<<dim3(2, M_ / 64), 256, 0, stream>>>(
            ctx16, w16_out, out_b, xs, res1, C_, C_);
        k_ln<<<M_ / 4, 256, 0, stream>>>(res1, ln1g, ln1b, nrm);
        for (int g = 0; g < G; ++g) {
            const float* nrm_g = nrm + (size_t)g * Mg * C_;
            k_gemm_mfma<EPI_GELU, false, true><<<dim3(8, Mg / 64), 256, 0, stream>>>(
                nrm_g, w16_1, b1, nullptr, h16, FF, C_);
            k_gemm_mfma<EPI_RES, true, false><<<dim3(2, Mg / 64), 256, 0, stream>>>(
                h16, w16_2, b2, nrm_g, res2 + (size_t)g * Mg * C_, C_, FF);
        }
        k_ln<<<M_ / 4, 256, 0, stream>>>(res2, ln2g, ln2b, tmp2);
        k_transpose_out<<<dim3(C_ / 32, F_ / 32, B_ * T_), tb, 0, stream>>>(tmp2, out);
    }
}